// Round 6
// baseline (196.979 us; speedup 1.0000x reference)
//
#include <hip/hip_runtime.h>

// Problem shape (fixed by the reference setup_inputs)
constexpr int B = 16, F = 16, H = 256, W = 256;
constexpr int HW = H * W;               // 65536
constexpr int SPATIAL = B * HW;         // 1,048,576 per-feature element count
constexpr int PLANE4 = HW / 4;          // 16384 float4 (or mask-dwords) per (b,f) plane
constexpr int BSTRIDE4 = F * PLANE4;    // 262144 per batch index
constexpr int FQ = 4;                   // features per quarter-wave

constexpr int NBLK = 2048;              // 8 blocks/CU queued -> self load-balancing
constexpr int NTHREADS = 256;           // 4 waves/block (finer scheduling granularity)
constexpr int NWAVES = NTHREADS / 64;
constexpr int TOTG = B * PLANE4;        // 262144 groups (group = 4 pixels x 16 features)
constexpr int SLOTS = NBLK * NWAVES * 16;   // 131072 (wave,l16) slots per sweep
constexpr int G = TOTG / SLOTS;         // 2 groups per thread
static_assert(G == 2, "kernel below is hand-scheduled for G==2");

// 50 values: s[16], c[16], dtot[16], sall_tot, call.
constexpr int NVALS = 50;

// R14 = R13 rerun with the amdgcn sched_barrier builtin (suspected container
// killer — failure signature matched R9's cooperative-launch death, and the
// builtin was the only exotic ingredient) replaced by a plain inline-asm
// memory-clobber fence. Same forcing: 24 loads must issue before any consume
// (loads can't sink past the fence; consumes data-depend on the loads).
// Quadrant under test: many blocks (balance) x deep forced ILP.
// Diagnostic: VGPR <80 in the counters means the forcing failed again.
struct Buf {
    unsigned int m[FQ];
    float4 a[FQ];
    float4 t[FQ];
};

__global__ __launch_bounds__(NTHREADS) void heatloss_main(
        const float4* __restrict__ inp, const float4* __restrict__ tgt,
        const unsigned int* __restrict__ msk, float* __restrict__ partials) {
    const int tid  = threadIdx.x;
    const int wave = tid >> 6;
    const int lane = tid & 63;
    const int l16  = lane & 15;
    const int q    = lane >> 4;              // quarter: features q*4 .. q*4+3
    const int slot0 = (blockIdx.x * NWAVES + wave) * 16 + l16;
    const int qoff  = q * (FQ * PLANE4);

    float s[FQ]  = {0.f, 0.f, 0.f, 0.f};
    float c[FQ]  = {0.f, 0.f, 0.f, 0.f};
    float dt[FQ] = {0.f, 0.f, 0.f, 0.f};
    float sall = 0.f, call = 0.f;

    auto load_group = [&](Buf& bf, int it) {
        const int slot = slot0 + it * SLOTS;
        const int base = (slot >> 14) * BSTRIDE4 + (slot & (PLANE4 - 1)) + qoff;
        #pragma unroll
        for (int j = 0; j < FQ; j++) bf.m[j] = msk[base + j * PLANE4];
        #pragma unroll
        for (int j = 0; j < FQ; j++) bf.a[j] = inp[base + j * PLANE4];
        #pragma unroll
        for (int j = 0; j < FQ; j++) bf.t[j] = tgt[base + j * PLANE4];
    };

    auto consume = [&](const Buf& bf) {
        unsigned int anyu = bf.m[0] | bf.m[1] | bf.m[2] | bf.m[3];
        anyu |= __shfl_xor(anyu, 16, 64);    // combine quarters...
        anyu |= __shfl_xor(anyu, 32, 64);    // ...-> any over all 16 features
        const float af0 = (anyu & 0x000000FFu) ? 1.f : 0.f;
        const float af1 = (anyu & 0x0000FF00u) ? 1.f : 0.f;
        const float af2 = (anyu & 0x00FF0000u) ? 1.f : 0.f;
        const float af3 = (anyu & 0xFF000000u) ? 1.f : 0.f;
        if (q == 0) call += (af0 + af1) + (af2 + af3);   // count each pixel once

        #pragma unroll
        for (int j = 0; j < FQ; j++) {
            const float4 a = bf.a[j];
            const float4 t = bf.t[j];
            const float d0 = fabsf(a.x - t.x);
            const float d1 = fabsf(a.y - t.y);
            const float d2 = fabsf(a.z - t.z);
            const float d3 = fabsf(a.w - t.w);
            const unsigned int mm = bf.m[j];
            const float m0 = (float)( mm        & 0xFFu);
            const float m1 = (float)((mm >> 8)  & 0xFFu);
            const float m2 = (float)((mm >> 16) & 0xFFu);
            const float m3 = (float)( mm >> 24);
            dt[j] += (d0 + d1) + (d2 + d3);
            s[j]  += m0 * d0 + m1 * d1 + m2 * d2 + m3 * d3;
            c[j]  += (m0 + m1) + (m2 + m3);
            sall  += af0 * d0 + af1 * d1 + af2 * d2 + af3 * d3;
        }
    };

    // Both groups loaded up front: 24 loads outstanding. The inline-asm
    // memory fence pins the schedule — loads cannot sink below it.
    Buf b0, b1;
    load_group(b0, 0);
    load_group(b1, 1);
    asm volatile("" ::: "memory");
    consume(b0);
    consume(b1);

    // Width-16 reduction for per-feature values (quarters hold disjoint features)
    __shared__ float red[NWAVES][NVALS];
    const int fbase = q * FQ;
    #pragma unroll
    for (int j = 0; j < FQ; j++) {
        float xs = s[j], xc = c[j], xd = dt[j];
        #pragma unroll
        for (int o = 8; o > 0; o >>= 1) {
            xs += __shfl_down(xs, o, 16);
            xc += __shfl_down(xc, o, 16);
            xd += __shfl_down(xd, o, 16);
        }
        if (l16 == 0) {
            red[wave][ 0 + fbase + j] = xs;
            red[wave][16 + fbase + j] = xc;
            red[wave][32 + fbase + j] = xd;
        }
    }
    // Full-wave reduction for the two scalars
    float xa = sall, xcl = call;
    #pragma unroll
    for (int o = 32; o > 0; o >>= 1) {
        xa  += __shfl_down(xa,  o, 64);
        xcl += __shfl_down(xcl, o, 64);
    }
    if (lane == 0) { red[wave][48] = xa; red[wave][49] = xcl; }
    __syncthreads();

    if (tid < NVALS) {
        float t = 0.f;
        #pragma unroll
        for (int w2 = 0; w2 < NWAVES; w2++) t += red[w2][tid];
        partials[tid * NBLK + blockIdx.x] = t;   // layout [50][NBLK]
    }
}

// Finalize: one block sums the 50x2048 partials and emits the loss.
__global__ __launch_bounds__(NTHREADS) void heatloss_final(
        const float* __restrict__ partials, float* __restrict__ out) {
    const int tid  = threadIdx.x;
    const int wave = tid >> 6;
    const int lane = tid & 63;
    __shared__ float vals[NVALS];
    for (int v = wave; v < NVALS; v += NWAVES) {
        const float* p = partials + v * NBLK;
        float x = 0.f;
        #pragma unroll
        for (int k = 0; k < NBLK / 64; k++) x += p[lane + k * 64];
        #pragma unroll
        for (int o = 32; o > 0; o >>= 1) x += __shfl_down(x, o, 64);
        if (lane == 0) vals[v] = x;
    }
    __syncthreads();
    if (tid == 0) {
        const float Nf = (float)SPATIAL;
        float lf = 0.f, lbg = 0.f;
        #pragma unroll
        for (int f = 0; f < F; f++) {
            const float sf = vals[f], cf = vals[16 + f], dtf = vals[32 + f];
            lf += (cf > 0.f) ? sf / cf : 0.f;
            const float sbg = dtf - sf, cbg = Nf - cf;
            lbg += (cbg > 0.f) ? sbg / cbg : 0.f;
        }
        const float sa = vals[48], cl = vals[49];
        const float lall = (cl > 0.f) ? sa / cl : 0.f;  // == mean_f(sa_f/call)*16
        out[0] = (lf / 16.f + lbg / 16.f + lall / 16.f) / 3.f;
    }
}

extern "C" void kernel_launch(void* const* d_in, const int* in_sizes, int n_in,
                              void* d_out, int out_size, void* d_ws, size_t ws_size,
                              hipStream_t stream) {
    const float4*       inp = (const float4*)d_in[0];
    const float4*       tgt = (const float4*)d_in[1];
    const unsigned int* msk = (const unsigned int*)d_in[2];   // jnp.bool_ -> 1 byte each
    float* out      = (float*)d_out;
    float* partials = (float*)d_ws;                  // [50][2048] = 400 KB

    heatloss_main<<<NBLK, NTHREADS, 0, stream>>>(inp, tgt, msk, partials);
    heatloss_final<<<1, NTHREADS, 0, stream>>>(partials, out);
}

// Round 7
// 192.099 us; speedup vs baseline: 1.0254x; 1.0254x over previous
//
#include <hip/hip_runtime.h>

// Problem shape (fixed by the reference setup_inputs)
constexpr int B = 16, F = 16, H = 256, W = 256;
constexpr int HW = H * W;               // 65536
constexpr int SPATIAL = B * HW;         // 1,048,576 per-feature element count
constexpr int PLANE4 = HW / 4;          // 16384 float4 (or mask-dwords) per (b,f) plane
constexpr int BSTRIDE4 = F * PLANE4;    // 262144 per batch index

constexpr int NBLK = 2048;              // 8 blocks/CU queued (proven best geometry)
constexpr int NTHREADS = 256;           // 4 waves/block
constexpr int NWAVES = NTHREADS / 64;
constexpr int G = 2;                    // float4-columns per thread
constexpr int TOT4 = B * PLANE4;        // 262144 (b,hw4) float4-columns
static_assert(NBLK * G * 64 == TOT4, "coverage must be exact");

// 50 values: s[16], c[16], dtot[16], sall_tot, call.
constexpr int NVALS = 50;

// R15: contiguity experiment. All prior rounds used lane>>4 feature-quarters,
// so every float4 wave-load spanned 4 DISCONTIGUOUS 256B segments (4 feature
// planes) -> 4 TA/L2 request bursts per instruction. Six schedule variants all
// pinned at ~2.6 TB/s delivered with VALU ~10% -> suspect the vmem address
// pipe, not data BW. Fix: features assigned per-WAVE (wave w -> features
// 4w..4w+3); 64 lanes walk consecutive float4s of ONE plane -> every float4
// wave-load is a single contiguous 1KB segment (masks: 256B). The cross-
// feature `any` OR moves to a small LDS exchange (1 write + 4 reads/dword,
// conflict-free, 1 barrier/iter). sall = af*dtot distributes over per-wave
// partial sums, so correctness is preserved with wave-local features.
__global__ __launch_bounds__(NTHREADS) void heatloss_main(
        const float4* __restrict__ inp, const float4* __restrict__ tgt,
        const unsigned int* __restrict__ msk, float* __restrict__ partials) {
    const int tid  = threadIdx.x;
    const int wave = tid >> 6;               // 0..3: owns features 4w..4w+3
    const int lane = tid & 63;
    const int foff = (wave * 4) * PLANE4;

    float s[4]  = {0.f, 0.f, 0.f, 0.f};
    float c[4]  = {0.f, 0.f, 0.f, 0.f};
    float dt[4] = {0.f, 0.f, 0.f, 0.f};
    float sall = 0.f, call = 0.f;

    __shared__ unsigned int anybuf[2][NWAVES][64];   // double-buffered: 1 barrier/iter

    #pragma unroll
    for (int it = 0; it < G; ++it) {
        const int slot = blockIdx.x * G + it;        // 64-lane-contiguous column run
        const int gidx = slot * 64 + lane;           // global (b,hw4) float4-column
        const int b    = gidx >> 14;                 // gidx / PLANE4
        const int hw4  = gidx & (PLANE4 - 1);
        const int base = b * BSTRIDE4 + foff + hw4;

        unsigned int m[4];
        float4 av[4], tv[4];
        #pragma unroll
        for (int j = 0; j < 4; j++) m[j] = msk[base + j * PLANE4];
        #pragma unroll
        for (int j = 0; j < 4; j++) av[j] = inp[base + j * PLANE4];
        #pragma unroll
        for (int j = 0; j < 4; j++) tv[j] = tgt[base + j * PLANE4];

        // any over all 16 features: per-wave OR, exchanged through LDS.
        const unsigned int anyw = m[0] | m[1] | m[2] | m[3];
        anybuf[it & 1][wave][lane] = anyw;
        __syncthreads();
        const unsigned int any = anybuf[it & 1][0][lane] | anybuf[it & 1][1][lane]
                               | anybuf[it & 1][2][lane] | anybuf[it & 1][3][lane];

        const float af0 = (any & 0x000000FFu) ? 1.f : 0.f;
        const float af1 = (any & 0x0000FF00u) ? 1.f : 0.f;
        const float af2 = (any & 0x00FF0000u) ? 1.f : 0.f;
        const float af3 = (any & 0xFF000000u) ? 1.f : 0.f;
        if (wave == 0) call += (af0 + af1) + (af2 + af3);  // count each pixel once

        #pragma unroll
        for (int j = 0; j < 4; j++) {
            const float4 a = av[j];
            const float4 t = tv[j];
            const float d0 = fabsf(a.x - t.x);
            const float d1 = fabsf(a.y - t.y);
            const float d2 = fabsf(a.z - t.z);
            const float d3 = fabsf(a.w - t.w);
            const unsigned int mm = m[j];
            const float m0 = (float)( mm        & 0xFFu);
            const float m1 = (float)((mm >> 8)  & 0xFFu);
            const float m2 = (float)((mm >> 16) & 0xFFu);
            const float m3 = (float)( mm >> 24);
            dt[j] += (d0 + d1) + (d2 + d3);
            s[j]  += m0 * d0 + m1 * d1 + m2 * d2 + m3 * d3;
            c[j]  += (m0 + m1) + (m2 + m3);
            sall  += af0 * d0 + af1 * d1 + af2 * d2 + af3 * d3;
        }
    }

    // Full-wave (width 64) reduction; each wave owns disjoint features.
    // red[w]: [0..3]=s, [4..7]=c, [8..11]=dt for features 4w..4w+3; [12]=sall, [13]=call
    __shared__ float red[NWAVES][14];
    #pragma unroll
    for (int j = 0; j < 4; j++) {
        float xs = s[j], xc = c[j], xd = dt[j];
        #pragma unroll
        for (int o = 32; o > 0; o >>= 1) {
            xs += __shfl_down(xs, o, 64);
            xc += __shfl_down(xc, o, 64);
            xd += __shfl_down(xd, o, 64);
        }
        if (lane == 0) {
            red[wave][0 + j] = xs;
            red[wave][4 + j] = xc;
            red[wave][8 + j] = xd;
        }
    }
    float xa = sall, xcl = call;
    #pragma unroll
    for (int o = 32; o > 0; o >>= 1) {
        xa  += __shfl_down(xa,  o, 64);
        xcl += __shfl_down(xcl, o, 64);
    }
    if (lane == 0) { red[wave][12] = xa; red[wave][13] = xcl; }
    __syncthreads();

    if (tid < NVALS) {
        float t;
        if (tid < 16) {                         // s[f]: owner wave f>>2
            t = red[tid >> 2][0 + (tid & 3)];
        } else if (tid < 32) {                  // c[f]
            const int f = tid - 16;
            t = red[f >> 2][4 + (f & 3)];
        } else if (tid < 48) {                  // dtot[f]
            const int f = tid - 32;
            t = red[f >> 2][8 + (f & 3)];
        } else if (tid == 48) {                 // sall
            t = (red[0][12] + red[1][12]) + (red[2][12] + red[3][12]);
        } else {                                // call
            t = (red[0][13] + red[1][13]) + (red[2][13] + red[3][13]);
        }
        partials[tid * NBLK + blockIdx.x] = t;  // layout [50][NBLK]
    }
}

// Finalize: one block sums the 50x2048 partials and emits the loss.
__global__ __launch_bounds__(NTHREADS) void heatloss_final(
        const float* __restrict__ partials, float* __restrict__ out) {
    const int tid  = threadIdx.x;
    const int wave = tid >> 6;
    const int lane = tid & 63;
    __shared__ float vals[NVALS];
    for (int v = wave; v < NVALS; v += NWAVES) {
        const float* p = partials + v * NBLK;
        float x = 0.f;
        #pragma unroll
        for (int k = 0; k < NBLK / 64; k++) x += p[lane + k * 64];
        #pragma unroll
        for (int o = 32; o > 0; o >>= 1) x += __shfl_down(x, o, 64);
        if (lane == 0) vals[v] = x;
    }
    __syncthreads();
    if (tid == 0) {
        const float Nf = (float)SPATIAL;
        float lf = 0.f, lbg = 0.f;
        #pragma unroll
        for (int f = 0; f < F; f++) {
            const float sf = vals[f], cf = vals[16 + f], dtf = vals[32 + f];
            lf += (cf > 0.f) ? sf / cf : 0.f;
            const float sbg = dtf - sf, cbg = Nf - cf;
            lbg += (cbg > 0.f) ? sbg / cbg : 0.f;
        }
        const float sa = vals[48], cl = vals[49];
        const float lall = (cl > 0.f) ? sa / cl : 0.f;  // == mean_f(sa_f/call)*16
        out[0] = (lf / 16.f + lbg / 16.f + lall / 16.f) / 3.f;
    }
}

extern "C" void kernel_launch(void* const* d_in, const int* in_sizes, int n_in,
                              void* d_out, int out_size, void* d_ws, size_t ws_size,
                              hipStream_t stream) {
    const float4*       inp = (const float4*)d_in[0];
    const float4*       tgt = (const float4*)d_in[1];
    const unsigned int* msk = (const unsigned int*)d_in[2];   // jnp.bool_ -> 1 byte each
    float* out      = (float*)d_out;
    float* partials = (float*)d_ws;                  // [50][2048] = 400 KB

    heatloss_main<<<NBLK, NTHREADS, 0, stream>>>(inp, tgt, msk, partials);
    heatloss_final<<<1, NTHREADS, 0, stream>>>(partials, out);
}